// Round 8
// baseline (109.376 us; speedup 1.0000x reference)
//
#include <hip/hip_runtime.h>

#define NROWS 8192
#define HALF_N 4096
#define DIM 512
#define INV_T 10.0f
#define NRB 64              // number of 128-row blocks
#define NBLOCKS 2080        // 64*65/2 upper-triangle block pairs

typedef __attribute__((ext_vector_type(4))) float f32x4;
typedef __attribute__((ext_vector_type(2))) long long2v;

// Kernel 1: L2-normalize rows of [f1;f2] -> fp8 e4m3 into Fa ONLY.
// Fa: fragment-major — panel p = row>>4 is 8 KB laid out as
// [chunk c=0..31][row&15][16B], where chunk c holds k-units {c&3, (c&3)+4}
// of k-group c>>2. Both A and B fragment loads in the GEMM read this layout
// as coalesced global b128 (quarter-wave = 256 B contiguous): the MFMA
// B-operand lane mapping (col=colid, k-chunk=quad) mirrors A's
// (row=colid, k-chunk=quad), and A,B are rows of the same matrix.
__global__ __launch_bounds__(256) void norm_cast_k(
    const float* __restrict__ f1, const float* __restrict__ f2,
    unsigned char* __restrict__ Fa, float* __restrict__ rowsum,
    float* __restrict__ out) {
  int wave = threadIdx.x >> 6;
  int lane = threadIdx.x & 63;
  int row = blockIdx.x * 4 + wave;
  const float* src = (row < HALF_N) ? (f1 + (size_t)row * DIM)
                                    : (f2 + (size_t)(row - HALF_N) * DIM);
  const float4* p = reinterpret_cast<const float4*>(src + lane * 8);
  float4 v0 = p[0];
  float4 v1 = p[1];
  float ss = v0.x*v0.x + v0.y*v0.y + v0.z*v0.z + v0.w*v0.w
           + v1.x*v1.x + v1.y*v1.y + v1.z*v1.z + v1.w*v1.w;
  #pragma unroll
  for (int off = 1; off < 64; off <<= 1) ss += __shfl_xor(ss, off);
  float scale = 1.0f / fmaxf(sqrtf(ss), 1e-12f);
  int lo = __builtin_amdgcn_cvt_pk_fp8_f32(v0.x * scale, v0.y * scale, 0, false);
  lo = __builtin_amdgcn_cvt_pk_fp8_f32(v0.z * scale, v0.w * scale, lo, true);
  int hi = __builtin_amdgcn_cvt_pk_fp8_f32(v1.x * scale, v1.y * scale, 0, false);
  hi = __builtin_amdgcn_cvt_pk_fp8_f32(v1.z * scale, v1.w * scale, hi, true);
  int2 val = make_int2(lo, hi);   // 8 fp8 bytes = k-unit u of group g
  int u = lane & 7;                     // k-unit within 64B group
  int g = lane >> 3;                    // k-group (0..7)
  int chunk = g * 4 + (u & 3);          // global 16B chunk index (0..31)
  int slot = u >> 2;                    // which 8B half of the chunk
  *reinterpret_cast<int2*>(Fa + (size_t)(row >> 4) * 8192 + chunk * 256 +
                           (row & 15) * 16 + slot * 8) = val;
  if (lane == 0) rowsum[row] = 0.0f;
  if (blockIdx.x == 0 && threadIdx.x == 0) out[0] = 0.0f;
}

// Kernel 2: symmetric upper-triangle sim GEMM (fp8 e4m3 16x16x32, non-scaled;
// the MX-scaled builtin spills v8i32 via scratch on this ROCm — R1-R3. Do not
// retry.)
//
// R8 structure: zero-sync K-loop (R7) + OCCUPANCY attack. R0/R4/R7 — three
// disjoint sync structures — all pinned at ~45 us, MfmaUtil ~29%, Occupancy
// ~30% (3 waves/SIMD at the (256,3) 170-reg cap). Diagnosis: latency hiding
// is wave-starved, not schedule-starved. Changes:
//  (a) __launch_bounds__(256,4): 128-reg cap -> 4 waves/SIMD (50%). Fits by
//      dropping the explicit prefetch (TLP replaces ILP: per-wave 32-MFMA
//      burst = 621 cyc/SIMD vs ~400 cyc L2 latency -> 4-way overlap
//      saturates the matrix pipe).
//  (b) SGPR addressing: fragment addr = uniform panel base (SGPR) +
//      lane loff (ONE shared VGPR) + kc*1024 imm (13-bit). Kills 16 pointer
//      VGPRs and the per-round fragment-copy v_movs.
//  (c) pairsim test hoisted behind block-uniform haspairs (cb==rb+32).
// Register budget: acc 64 (AGPR side) + af/bf 32 + loff/misc ~12 < 128.
__global__ __launch_bounds__(256, 4) void sym_gemm_k(
    const unsigned char* __restrict__ Fa,
    float* __restrict__ rowsum, float* __restrict__ pairsim) {
  // XCD-contiguous remap: each XCD (bx%8) gets a contiguous 260-block range
  int bx = blockIdx.x;
  int gbx = (bx & 7) * (NBLOCKS / 8) + (bx >> 3);
  int rb = 0, rem = gbx;
  while (rem >= NRB - rb) { rem -= NRB - rb; ++rb; }
  const int cb = rb + rem;
  const int row0 = rb * 128, col0 = cb * 128;
  const bool haspairs = (cb == rb + 32);   // only these tiles touch the
                                           // (i, i+HALF_N) diagonal pairs

  const int tid = threadIdx.x;
  const int wave = tid >> 6;
  const int lane = tid & 63;
  const int quad = lane >> 4;
  const int colid = lane & 15;
  const int wr0 = (wave >> 1) * 64;   // wave's row offset within tile
  const int wc0 = (wave & 1) * 64;    // wave's col offset within tile

  __shared__ float redrow[128];
  __shared__ float redcol[128];
  if (tid < 128) redrow[tid] = 0.0f;
  else           redcol[tid - 128] = 0.0f;

  // Uniform panel bases (SGPR) + one lane-varying offset (VGPR).
  // Fragment t of operand A lives at Fa + (panelA+t)*8192 + kc*1024 + loff;
  // quarter-wave (fixed quad, colid 0..15) reads 256 B contiguous.
  const int panelA = (row0 + wr0) >> 4;    // wave-uniform
  const int panelB = (col0 + wc0) >> 4;    // wave-uniform
  const int loff = quad * 256 + colid * 16;
  const unsigned char* baseA = Fa + (size_t)panelA * 8192;
  const unsigned char* baseB = Fa + (size_t)panelB * 8192;

  f32x4 acc[4][4];
  #pragma unroll
  for (int t = 0; t < 4; ++t)
    #pragma unroll
    for (int u = 0; u < 4; ++u) acc[t][u] = (f32x4){0.f, 0.f, 0.f, 0.f};

  #pragma unroll
  for (int kc = 0; kc < 8; ++kc) {
    long2v af[4], bf[4];
    #pragma unroll
    for (int t = 0; t < 4; ++t)
      af[t] = *reinterpret_cast<const long2v*>(
          baseA + (size_t)t * 8192 + kc * 1024 + loff);
    #pragma unroll
    for (int u = 0; u < 4; ++u)
      bf[u] = *reinterpret_cast<const long2v*>(
          baseB + (size_t)u * 8192 + kc * 1024 + loff);
    #pragma unroll
    for (int s = 0; s < 2; ++s)
      #pragma unroll
      for (int t = 0; t < 4; ++t)
        #pragma unroll
        for (int u = 0; u < 4; ++u)
          acc[t][u] = __builtin_amdgcn_mfma_f32_16x16x32_fp8_fp8(
              af[t][s], bf[u][s], acc[t][u], 0, 0, 0);
  }

  // One barrier in the whole kernel: makes the redrow/redcol zero-init
  // visible before any wave's atomic accumulation.
  __syncthreads();

  // Epilogue. C/D layout: col = lane&15, row = quad*4 + reg (m89-verified,
  // dtype-independent on gfx950).
  float re[4][4];
  float ce[4];
  #pragma unroll
  for (int t = 0; t < 4; ++t)
    #pragma unroll
    for (int r = 0; r < 4; ++r) re[t][r] = 0.0f;
  #pragma unroll
  for (int u = 0; u < 4; ++u) ce[u] = 0.0f;

  #pragma unroll
  for (int t = 0; t < 4; ++t) {
    #pragma unroll
    for (int u = 0; u < 4; ++u) {
      f32x4 a = acc[t][u];
      const int gc = col0 + wc0 + u * 16 + colid;
      #pragma unroll
      for (int r = 0; r < 4; ++r) {
        int grow = row0 + wr0 + t * 16 + quad * 4 + r;
        float sim = a[r] * INV_T;
        float e = (gc > grow) ? __expf(sim) : 0.0f;  // strict upper triangle
        re[t][r] += e;
        ce[u] += e;
        if (haspairs && gc == grow + HALF_N && grow < HALF_N) {
          pairsim[grow] = sim;         // unique writer per pair
          pairsim[gc] = sim;
        }
      }
    }
  }

  // Row sums: reduce across the 16 col-lanes, LDS-accumulate.
  #pragma unroll
  for (int t = 0; t < 4; ++t)
    #pragma unroll
    for (int r = 0; r < 4; ++r) {
      float v = re[t][r];
      v += __shfl_xor(v, 1); v += __shfl_xor(v, 2);
      v += __shfl_xor(v, 4); v += __shfl_xor(v, 8);
      if (colid == 0) atomicAdd(&redrow[wr0 + t * 16 + quad * 4 + r], v);
    }
  // Col sums: reduce across the 4 quads (this wave's 64 rows).
  #pragma unroll
  for (int u = 0; u < 4; ++u) {
    float v = ce[u];
    v += __shfl_xor(v, 16); v += __shfl_xor(v, 32);
    if (lane < 16) atomicAdd(&redcol[wc0 + u * 16 + colid], v);
  }
  __syncthreads();
  if (tid < 128) atomicAdd(&rowsum[row0 + tid], redrow[tid]);
  else           atomicAdd(&rowsum[col0 + tid - 128], redcol[tid - 128]);
}

// Kernel 3: loss partials. 32 blocks x 256 threads, one row each;
// per-wave reduce then one atomicAdd per wave into out (zeroed in kernel 1).
__global__ __launch_bounds__(256) void finalize_k(
    const float* __restrict__ rowsum, const float* __restrict__ pairsim,
    float* __restrict__ out) {
  int i = blockIdx.x * 256 + threadIdx.x;
  float local = logf(rowsum[i]) - pairsim[i];
  #pragma unroll
  for (int off = 1; off < 64; off <<= 1) local += __shfl_xor(local, off);
  if ((threadIdx.x & 63) == 0)
    atomicAdd(out, local * (1.0f / (float)NROWS));
}

extern "C" void kernel_launch(void* const* d_in, const int* in_sizes, int n_in,
                              void* d_out, int out_size, void* d_ws, size_t ws_size,
                              hipStream_t stream) {
  const float* f1 = (const float*)d_in[0];
  const float* f2 = (const float*)d_in[1];
  unsigned char* Fa = (unsigned char*)d_ws;                     // 4 MB fp8
  float* rowsum = (float*)(Fa + (size_t)NROWS * DIM);
  float* pairsim = rowsum + NROWS;
  float* out = (float*)d_out;

  norm_cast_k<<<NROWS / 4, 256, 0, stream>>>(f1, f2, Fa, rowsum, out);
  sym_gemm_k<<<NBLOCKS, 256, 0, stream>>>(Fa, rowsum, pairsim);
  finalize_k<<<NROWS / 256, 256, 0, stream>>>(rowsum, pairsim, out);
}